// Round 11
// baseline (336.637 us; speedup 1.0000x reference)
//
#include <hip/hip_runtime.h>
#include <math.h>

#define NN 40000
#define HD 128
#define NE 640000
#define MINN 1e-15f
#define NSB 157     // ceil(NN/256) scan chunks
#define GB  2500    // 16-row tiles
#define ZSB 625     // deferred-zstep blocks appended to gw1 (625*4 waves = 2500 tiles)
#define HB_BLK 512  // hist blocks appended to fc0 dispatch

typedef __attribute__((ext_vector_type(8))) short bf16x8;
typedef __attribute__((ext_vector_type(4))) float f32x4;

__device__ __forceinline__ float red16(float v){
  v += __shfl_xor(v, 1, 64); v += __shfl_xor(v, 2, 64);
  v += __shfl_xor(v, 4, 64); v += __shfl_xor(v, 8, 64);
  return v;
}

__device__ __forceinline__ float bf2f(short h){
  return __uint_as_float(((unsigned)(unsigned short)h) << 16);
}
__device__ __forceinline__ short f2bf(float v){
  unsigned u = __float_as_uint(v);
  u += 0x7FFF + ((u >> 16) & 1);       // RNE
  return (short)(u >> 16);
}

// gather accumulate: 8 bf16 cols from one uint4 row-chunk
#define GACC(A,V) \
  A[0] += __uint_as_float((V).x << 16); A[1] += __uint_as_float((V).x & 0xffff0000u); \
  A[2] += __uint_as_float((V).y << 16); A[3] += __uint_as_float((V).y & 0xffff0000u); \
  A[4] += __uint_as_float((V).z << 16); A[5] += __uint_as_float((V).z & 0xffff0000u); \
  A[6] += __uint_as_float((V).w << 16); A[7] += __uint_as_float((V).w & 0xffff0000u);

// ---- A rows (rb+l15, cols ks*32+kg*8..+8) from global row-major [.,128] ----
__device__ __forceinline__ void loadA_g(const float* __restrict__ A, long rb,
                                        int l15, int kg, float av[4][8]){
  #pragma unroll
  for (int ks = 0; ks < 4; ++ks){
    const float* ap = A + (rb + l15)*HD + ks*32 + kg*8;
    float4 a0 = *(const float4*)ap;
    float4 a1 = *(const float4*)(ap + 4);
    av[ks][0]=a0.x; av[ks][1]=a0.y; av[ks][2]=a0.z; av[ks][3]=a0.w;
    av[ks][4]=a1.x; av[ks][5]=a1.y; av[ks][6]=a1.z; av[ks][7]=a1.w;
  }
}

// ---- split-bf16 3-term MFMA: acc = A(f32 via hi+lo) @ W^T ----
__device__ __forceinline__ void mfma_core(const float av[4][8],
    const bf16x8* __restrict__ bh, const bf16x8* __restrict__ bl,
    int lane, f32x4 acc[8]){
  #pragma unroll
  for (int ct = 0; ct < 8; ++ct){
    acc[ct][0]=0.f; acc[ct][1]=0.f; acc[ct][2]=0.f; acc[ct][3]=0.f;
  }
  #pragma unroll
  for (int ks = 0; ks < 4; ++ks){
    bf16x8 ah, al;
    #pragma unroll
    for (int j = 0; j < 8; ++j){
      float v = av[ks][j];
      short hh = f2bf(v);
      short ll = f2bf(v - bf2f(hh));
      ah[j] = hh; al[j] = ll;
    }
    #pragma unroll
    for (int ct = 0; ct < 8; ++ct){
      bf16x8 bhv = bh[(ks*8 + ct)*64 + lane];
      bf16x8 blv = bl[(ks*8 + ct)*64 + lane];
      acc[ct] = __builtin_amdgcn_mfma_f32_16x16x32_bf16(ah, bhv, acc[ct], 0, 0, 0);
      acc[ct] = __builtin_amdgcn_mfma_f32_16x16x32_bf16(al, bhv, acc[ct], 0, 0, 0);
      acc[ct] = __builtin_amdgcn_mfma_f32_16x16x32_bf16(ah, blv, acc[ct], 0, 0, 0);
    }
  }
}

__device__ __forceinline__ void biasrelu(f32x4 acc[8], const float* __restrict__ bias,
                                         int l15, bool relu){
  #pragma unroll
  for (int ct = 0; ct < 8; ++ct){
    float bb = bias[ct*16 + l15];
    #pragma unroll
    for (int q = 0; q < 4; ++q){
      float v = acc[ct][q] + bb;
      if (relu) v = fmaxf(v, 0.f);
      acc[ct][q] = v;
    }
  }
}

// ---- full hyperbolic z-update for one 16-row tile, one wave ----
// hv[q][ct] holds the post-relu h values (row rb+kg*4+q, col ct*16+l15).
template<bool ZFIRST>
__device__ __forceinline__ void zstep_tile(const float hv[4][8],
    const float* __restrict__ zpin, const float* __restrict__ zcin,
    float* __restrict__ zout, const float* __restrict__ pvec,
    float scaling, long rb, int l15, int kg){
  float pvr[8]; float pq = 0.f;
  #pragma unroll
  for (int ct = 0; ct < 8; ++ct){
    float tv = pvec[ct*16 + l15];
    pvr[ct] = tv; pq = fmaf(tv, tv, pq);
  }
  pq = red16(pq);
  float qi = 1.0f / fmaxf(sqrtf(pq), MINN);
  #pragma unroll
  for (int ct = 0; ct < 8; ++ct) pvr[ct] *= qi;

  #pragma unroll
  for (int q = 0; q < 4; ++q){
    const long row = rb + kg*4 + q;
    float zc[8], zp[8];
    #pragma unroll
    for (int ct = 0; ct < 8; ++ct) zc[ct] = zcin[row*HD + ct*16 + l15];
    if constexpr (!ZFIRST){
      #pragma unroll
      for (int ct = 0; ct < 8; ++ct) zp[ct] = zpin[row*HD + ct*16 + l15];
    } else {
      #pragma unroll
      for (int ct = 0; ct < 8; ++ct) zp[ct] = 0.f;
    }
    float hh = 0.f, cc = 0.f;
    #pragma unroll
    for (int ct = 0; ct < 8; ++ct){
      hh = fmaf(hv[q][ct], hv[q][ct], hh);
      cc = fmaf(zc[ct], zc[ct], cc);
    }
    hh = red16(hh); cc = red16(cc);
    float zs = scaling / sqrtf(hh);
    float di = 1.0f / fmaxf(cc, MINN);
    float r2 = cc*di*di - 1.0f;
    float a[8], u[8]; float uu = 0.f;
    #pragma unroll
    for (int ct = 0; ct < 8; ++ct){
      a[ct] = zc[ct]*di;
      u[ct] = zp[ct] - a[ct];
      uu = fmaf(u[ct], u[ct], uu);
    }
    uu = red16(uu);
    float f = r2 / fmaxf(uu, MINN);
    float zpar[8]; float pn2 = 0.f;
    #pragma unroll
    for (int ct = 0; ct < 8; ++ct){
      zpar[ct] = fmaf(f, u[ct], a[ct]);
      pn2 = fmaf(zpar[ct], zpar[ct], pn2);
    }
    pn2 = red16(pn2);
    float pinv = 1.0f / fmaxf(sqrtf(pn2), MINN);
    float rv[8], zch[8]; float rz = 0.f, rr = 0.f;
    #pragma unroll
    for (int ct = 0; ct < 8; ++ct){
      zch[ct] = hv[q][ct]*zs;
      rv[ct] = pvr[ct] - zpar[ct]*pinv;
      rz = fmaf(rv[ct], zch[ct], rz);
      rr = fmaf(rv[ct], rv[ct], rr);
    }
    rz = red16(rz); rr = red16(rr);
    float mm = rz / rr;
    float u2[8]; float uu2 = 0.f;
    #pragma unroll
    for (int ct = 0; ct < 8; ++ct){
      float z2 = fmaf(-2.0f*mm, rv[ct], zch[ct]);
      u2[ct] = z2 - a[ct];
      uu2 = fmaf(u2[ct], u2[ct], uu2);
    }
    uu2 = red16(uu2);
    float f2 = r2 / fmaxf(uu2, MINN);
    #pragma unroll
    for (int ct = 0; ct < 8; ++ct)
      zout[row*HD + ct*16 + l15] = fmaf(f2, u2[ct], a[ct]);
  }
}

// ---------------- K1: weight prep (blocks 0..255) + zero cnt/part2 (blocks 256+) ----
__global__ __launch_bounds__(64) void zero_prep_k(const float* __restrict__ fc0_w,
    const float* __restrict__ w1, const float* __restrict__ w2,
    const float* __restrict__ fco_w, bf16x8* __restrict__ bhi,
    bf16x8* __restrict__ blo, int* __restrict__ cnt, float* __restrict__ part2){
  int bid = blockIdx.x;
  if (bid < 256){
    int gid = bid*64 + threadIdx.x;    // 0..16383
    int widx = gid >> 11;
    const float* W;
    if (widx == 0)      W = fc0_w;
    else if (widx <= 3) W = w1 + (size_t)(widx-1)*HD*HD;
    else if (widx <= 6) W = w2 + (size_t)(widx-4)*HD*HD;
    else                W = fco_w;
    int f  = gid & 2047;
    int ln = f & 63;
    int ct = (f >> 6) & 7;
    int ks = f >> 9;
    int n  = ct*16 + (ln & 15);
    int k0 = ks*32 + (ln >> 4)*8;
    bf16x8 hv, lv;
    #pragma unroll
    for (int j = 0; j < 8; ++j){
      float v = W[n*HD + k0 + j];
      short hh = f2bf(v);
      short ll = f2bf(v - bf2f(hh));
      hv[j] = hh; lv[j] = ll;
    }
    bhi[widx*2048 + f] = hv; blo[widx*2048 + f] = lv;
  } else {
    int i = (bid-256)*64 + threadIdx.x;
    const int st = 161*64;
    for (int j = i; j < NN; j += st) cnt[j] = 0;
    for (int j = i; j < 3*2048; j += st) part2[j] = 0.f;
  }
}

// ---------------- K2: fc0 tiles (blocks 0..2499) + edge histogram (blocks 2500+) ----
__global__ __launch_bounds__(64) void fc0hist_k(const float* __restrict__ x,
    const int* __restrict__ dst, int* __restrict__ cnt,
    const bf16x8* __restrict__ bhi, const bf16x8* __restrict__ blo,
    const float* __restrict__ fc0_b, float* __restrict__ h,
    unsigned short* __restrict__ hb, float* __restrict__ zB, float scaling){
  int bid = blockIdx.x;
  if (bid >= GB){
    int i = (bid - GB)*64 + threadIdx.x;
    const int st = HB_BLK*64;
    for (; i < NE; i += st) atomicAdd(&cnt[dst[i]], 1);
    return;
  }
  const int lane = threadIdx.x;
  const int l15 = lane & 15, kg = lane >> 4;
  const long rb = (long)bid*16;
  float av[4][8]; loadA_g(x, rb, l15, kg, av);
  f32x4 acc[8]; mfma_core(av, bhi, blo, lane, acc);
  biasrelu(acc, fc0_b, l15, true);
  #pragma unroll
  for (int ct = 0; ct < 8; ++ct)
    #pragma unroll
    for (int q = 0; q < 4; ++q){
      float v = acc[ct][q];
      long row = rb + kg*4 + q;
      h[row*HD + ct*16 + l15] = v;
      hb[row*HD + ct*16 + l15] = (unsigned short)f2bf(v);
    }
  #pragma unroll
  for (int q = 0; q < 4; ++q){
    float ss = 0.f;
    #pragma unroll
    for (int ct = 0; ct < 8; ++ct) ss = fmaf(acc[ct][q], acc[ct][q], ss);
    ss = red16(ss);
    float sc2 = scaling / sqrtf(ss);
    long row = rb + kg*4 + q;
    #pragma unroll
    for (int ct = 0; ct < 8; ++ct)
      zB[row*HD + ct*16 + l15] = acc[ct][q]*sc2;
  }
}

// ---------------- K3: merged full scan ----------------
__global__ __launch_bounds__(256) void scanall_k(const int* __restrict__ cnt,
    int* __restrict__ ptr, int* __restrict__ fil){
  __shared__ int s[256];
  const int b = blockIdx.x, t = threadIdx.x;
  const int lim = b*256;
  int acc = 0;
  for (int i = t; i < lim; i += 256) acc += cnt[i];
  s[t] = acc; __syncthreads();
  for (int off = 128; off; off >>= 1){
    if (t < off) s[t] += s[t+off];
    __syncthreads();
  }
  const int pre = s[0];
  __syncthreads();
  const int idx = lim + t;
  int v = (idx < NN) ? cnt[idx] : 0;
  s[t] = v; __syncthreads();
  for (int off = 1; off < 256; off <<= 1){
    int x = (t >= off) ? s[t-off] : 0;
    __syncthreads(); s[t] += x; __syncthreads();
  }
  if (idx < NN){
    int v2 = pre + s[t] - v;
    ptr[idx] = v2; fil[idx] = v2;
  }
  if (b == NSB-1 && t == 255) ptr[NN] = pre + s[255];
}

// ---------------- K4: fill edge buckets ----------------
__global__ void fill_k(const int* __restrict__ src, const int* __restrict__ dst,
    int* __restrict__ fill, unsigned short* __restrict__ eidx, int ne){
  int i = blockIdx.x*blockDim.x + threadIdx.x;
  int st = gridDim.x*blockDim.x;
  for (; i < ne; i += st){
    int d = dst[i];
    int pos = atomicAdd(&fill[d], 1);
    eidx[pos] = (unsigned short)src[i];
  }
}

// ---------------- K5: gather + w1 GEMM, 4 waves/WG (+ deferred prev-layer zstep) ----
// Blocks 0..GB-1: verbatim R6 gather+GEMM.
// ZS: blocks GB..GB+ZSB-1 (4 waves, 1 tile/wave) run the PREVIOUS layer's
// zstep reading h from global — independent work filling idle latency slots.
template<bool ZS, bool ZF>
__global__ __launch_bounds__(256) void gw1_k(const float* __restrict__ h,
    const bf16x8* __restrict__ bhi, const bf16x8* __restrict__ blo,
    const float* __restrict__ bias, float* __restrict__ t,
    float* __restrict__ part2, const uint4* __restrict__ hb4,
    const int* __restrict__ gptr, const unsigned short* __restrict__ eidx,
    const float* __restrict__ zpin, const float* __restrict__ zcin,
    float* __restrict__ zout, const float* __restrict__ pvec, float scaling)
{
  __shared__ float tl[16*132];
  const int tid = threadIdx.x;
  const int lane = tid & 63;
  const int wv = tid >> 6;
  const int l15 = lane & 15, kg = lane >> 4;

  if (ZS && blockIdx.x >= GB){
    // ---- deferred zstep: tile zt per wave ----
    const int zt = (blockIdx.x - GB)*4 + wv;   // 625*4 = 2500 exact
    const long rb = (long)zt*16;
    float hv[4][8];
    #pragma unroll
    for (int q = 0; q < 4; ++q){
      const long row = rb + kg*4 + q;
      #pragma unroll
      for (int ct = 0; ct < 8; ++ct)
        hv[q][ct] = h[row*HD + ct*16 + l15];
    }
    zstep_tile<ZF>(hv, zpin, zcin, zout, pvec, scaling, rb, l15, kg);
    return;
  }

  const long rb = (long)blockIdx.x*16;

  // ---- gather: lane-group (wv,kg) owns tile row r = wv*4+kg ----
  {
    const int r = wv*4 + kg;
    const long node = rb + r;
    int beg = gptr[node], end = gptr[node+1];
    const float4* selfp = (const float4*)(h + node*HD) + l15*2;
    float4 s0 = selfp[0], s1 = selfp[1];
    float ga[8] = {s0.x,s0.y,s0.z,s0.w,s1.x,s1.y,s1.z,s1.w};
    int e = beg;
    for (; e + 8 <= end; e += 8){
      int i0 = eidx[e],   i1 = eidx[e+1], i2 = eidx[e+2], i3 = eidx[e+3];
      int i4 = eidx[e+4], i5 = eidx[e+5], i6 = eidx[e+6], i7 = eidx[e+7];
      uint4 v0 = hb4[(long)i0*16 + l15];
      uint4 v1 = hb4[(long)i1*16 + l15];
      uint4 v2 = hb4[(long)i2*16 + l15];
      uint4 v3 = hb4[(long)i3*16 + l15];
      uint4 v4 = hb4[(long)i4*16 + l15];
      uint4 v5 = hb4[(long)i5*16 + l15];
      uint4 v6 = hb4[(long)i6*16 + l15];
      uint4 v7 = hb4[(long)i7*16 + l15];
      GACC(ga,v0) GACC(ga,v1) GACC(ga,v2) GACC(ga,v3)
      GACC(ga,v4) GACC(ga,v5) GACC(ga,v6) GACC(ga,v7)
    }
    if (e + 4 <= end){
      int i0 = eidx[e], i1 = eidx[e+1], i2 = eidx[e+2], i3 = eidx[e+3];
      uint4 v0 = hb4[(long)i0*16 + l15];
      uint4 v1 = hb4[(long)i1*16 + l15];
      uint4 v2 = hb4[(long)i2*16 + l15];
      uint4 v3 = hb4[(long)i3*16 + l15];
      GACC(ga,v0) GACC(ga,v1) GACC(ga,v2) GACC(ga,v3)
      e += 4;
    }
    for (; e < end; ++e){
      uint4 v = hb4[(long)eidx[e]*16 + l15];
      GACC(ga,v)
    }
    float4* tp = (float4*)(tl + r*132 + l15*8);
    float4 o0 = {ga[0],ga[1],ga[2],ga[3]};
    float4 o1 = {ga[4],ga[5],ga[6],ga[7]};
    tp[0] = o0; tp[1] = o1;
  }
  __syncthreads();
  if (wv != 0) return;

  // ---- wave 0: GEMM + bias/relu + stats + t-write ----
  float av[4][8];
  #pragma unroll
  for (int ks = 0; ks < 4; ++ks){
    const float* ap = tl + l15*132 + ks*32 + kg*8;
    float4 a0 = *(const float4*)ap;
    float4 a1 = *(const float4*)(ap + 4);
    av[ks][0]=a0.x; av[ks][1]=a0.y; av[ks][2]=a0.z; av[ks][3]=a0.w;
    av[ks][4]=a1.x; av[ks][5]=a1.y; av[ks][6]=a1.z; av[ks][7]=a1.w;
  }
  f32x4 acc[8]; mfma_core(av, bhi, blo, lane, acc);
  biasrelu(acc, bias, l15, true);

  #pragma unroll
  for (int ct = 0; ct < 8; ++ct){
    float s = 0.f, q2 = 0.f;
    #pragma unroll
    for (int q = 0; q < 4; ++q){
      float v = acc[ct][q];
      s += v; q2 = fmaf(v, v, q2);
    }
    s  += __shfl_xor(s, 16, 64);  s  += __shfl_xor(s, 32, 64);
    q2 += __shfl_xor(q2, 16, 64); q2 += __shfl_xor(q2, 32, 64);
    if (kg == 0){
      const int slot = (blockIdx.x & 7)*256;
      atomicAdd(&part2[slot + ct*16 + l15], s);
      atomicAdd(&part2[slot + 128 + ct*16 + l15], q2);
    }
  }

  #pragma unroll
  for (int ct = 0; ct < 8; ++ct)
    #pragma unroll
    for (int q = 0; q < 4; ++q)
      t[(rb + kg*4 + q)*HD + ct*16 + l15] = acc[ct][q];
}

// ---------------- K6: BN finalize: part2[8][256] -> scale/shift (layer-indexed) ----
__global__ __launch_bounds__(256) void bnfin_k(const float* __restrict__ part2,
    const float* __restrict__ g, const float* __restrict__ b,
    float* __restrict__ scale, float* __restrict__ shift){
  __shared__ float sm[256];
  float tot = 0.f;
  #pragma unroll
  for (int r = 0; r < 8; ++r) tot += part2[r*256 + threadIdx.x];
  sm[threadIdx.x] = tot;
  __syncthreads();
  if (threadIdx.x < 128){
    int c = threadIdx.x;
    float s = sm[c], q = sm[c + 128];
    float mu  = s * (1.0f/NN);
    float var = q * (1.0f/NN) - mu*mu;
    float istd = rsqrtf(var + 1e-5f);
    float scv = g[c]*istd;
    scale[c] = scv;
    shift[c] = fmaf(-mu, scv, b[c]);
  }
}

// ---------------- K7: w2 GEMM only (layers 0,1): h = relu(BN(t) @ w2^T + b2) ----
__global__ __launch_bounds__(64) void w2g_k(const float* __restrict__ A,
    const bf16x8* __restrict__ bhi, const bf16x8* __restrict__ blo,
    const float* __restrict__ bias, const float* __restrict__ scale,
    const float* __restrict__ shift, float* __restrict__ hout,
    unsigned short* __restrict__ hbout)
{
  const int lane = threadIdx.x;
  const int l15 = lane & 15, kg = lane >> 4;
  const long rb = (long)blockIdx.x*16;

  float av[4][8];
  loadA_g(A, rb, l15, kg, av);
  #pragma unroll
  for (int ks = 0; ks < 4; ++ks){
    const int k0 = ks*32 + kg*8;
    float4 s0 = *(const float4*)(scale + k0);
    float4 s1 = *(const float4*)(scale + k0 + 4);
    float4 h0 = *(const float4*)(shift + k0);
    float4 h1 = *(const float4*)(shift + k0 + 4);
    float sc[8] = {s0.x,s0.y,s0.z,s0.w,s1.x,s1.y,s1.z,s1.w};
    float sh[8] = {h0.x,h0.y,h0.z,h0.w,h1.x,h1.y,h1.z,h1.w};
    #pragma unroll
    for (int j = 0; j < 8; ++j)
      av[ks][j] = fmaf(av[ks][j], sc[j], sh[j]);
  }
  f32x4 acc[8];
  mfma_core(av, bhi, blo, lane, acc);
  biasrelu(acc, bias, l15, true);
  #pragma unroll
  for (int ct = 0; ct < 8; ++ct)
    #pragma unroll
    for (int q = 0; q < 4; ++q){
      float v = acc[ct][q];
      long row = rb + kg*4 + q;
      hout[row*HD + ct*16 + l15] = v;
      hbout[row*HD + ct*16 + l15] = (unsigned short)f2bf(v);
    }
}

// ---------------- K8: w2 GEMM + fused zstep (layer 2; R6-proven form) ----------
__global__ __launch_bounds__(64) void w2z2_k(const float* __restrict__ A,
    const bf16x8* __restrict__ bhi, const bf16x8* __restrict__ blo,
    const float* __restrict__ bias, const float* __restrict__ scale,
    const float* __restrict__ shift, float* __restrict__ zout, float scaling,
    const float* __restrict__ zpin, const float* __restrict__ zcin,
    const float* __restrict__ pvec)
{
  const int lane = threadIdx.x;
  const int l15 = lane & 15, kg = lane >> 4;
  const long rb = (long)blockIdx.x*16;

  float av[4][8];
  loadA_g(A, rb, l15, kg, av);

  // zstep operand prefetch before the MFMA stream (R5-proven)
  float zc_a[4][8], zp_a[4][8], pvr8[8];
  #pragma unroll
  for (int q = 0; q < 4; ++q){
    const long row = rb + kg*4 + q;
    #pragma unroll
    for (int ct = 0; ct < 8; ++ct){
      zc_a[q][ct] = zcin[row*HD + ct*16 + l15];
      zp_a[q][ct] = zpin[row*HD + ct*16 + l15];
    }
  }
  #pragma unroll
  for (int ct = 0; ct < 8; ++ct) pvr8[ct] = pvec[ct*16 + l15];

  #pragma unroll
  for (int ks = 0; ks < 4; ++ks){
    const int k0 = ks*32 + kg*8;
    float4 s0 = *(const float4*)(scale + k0);
    float4 s1 = *(const float4*)(scale + k0 + 4);
    float4 h0 = *(const float4*)(shift + k0);
    float4 h1 = *(const float4*)(shift + k0 + 4);
    float sc[8] = {s0.x,s0.y,s0.z,s0.w,s1.x,s1.y,s1.z,s1.w};
    float sh[8] = {h0.x,h0.y,h0.z,h0.w,h1.x,h1.y,h1.z,h1.w};
    #pragma unroll
    for (int j = 0; j < 8; ++j)
      av[ks][j] = fmaf(av[ks][j], sc[j], sh[j]);
  }
  f32x4 acc[8];
  mfma_core(av, bhi, blo, lane, acc);
  biasrelu(acc, bias, l15, true);

  // zstep (verbatim R6 math; hv from acc)
  float pq = 0.f;
  #pragma unroll
  for (int ct = 0; ct < 8; ++ct) pq = fmaf(pvr8[ct], pvr8[ct], pq);
  pq = red16(pq);
  float qi = 1.0f / fmaxf(sqrtf(pq), MINN);
  #pragma unroll
  for (int ct = 0; ct < 8; ++ct) pvr8[ct] *= qi;

  #pragma unroll
  for (int q = 0; q < 4; ++q){
    const long row = rb + kg*4 + q;
    float zc[8], zp[8];
    #pragma unroll
    for (int ct = 0; ct < 8; ++ct){ zc[ct] = zc_a[q][ct]; zp[ct] = zp_a[q][ct]; }
    float hh = 0.f, cc = 0.f;
    #pragma unroll
    for (int ct = 0; ct < 8; ++ct){
      hh = fmaf(acc[ct][q], acc[ct][q], hh);
      cc = fmaf(zc[ct], zc[ct], cc);
    }
    hh = red16(hh); cc = red16(cc);
    float zs = scaling / sqrtf(hh);
    float di = 1.0f / fmaxf(cc, MINN);
    float r2 = cc*di*di - 1.0f;
    float a[8], u[8]; float uu = 0.f;
    #pragma unroll
    for (int ct = 0; ct < 8; ++ct){
      a[ct] = zc[ct]*di;
      u[ct] = zp[ct] - a[ct];
      uu = fmaf(u[ct], u[ct], uu);
    }
    uu = red16(uu);
    float f = r2 / fmaxf(uu, MINN);
    float zpar[8]; float pn2 = 0.f;
    #pragma unroll
    for (int ct = 0; ct < 8; ++ct){
      zpar[ct] = fmaf(f, u[ct], a[ct]);
      pn2 = fmaf(zpar[ct], zpar[ct], pn2);
    }
    pn2 = red16(pn2);
    float pinv = 1.0f / fmaxf(sqrtf(pn2), MINN);
    float rv[8], zch[8]; float rz = 0.f, rr = 0.f;
    #pragma unroll
    for (int ct = 0; ct < 8; ++ct){
      zch[ct] = acc[ct][q]*zs;
      rv[ct] = pvr8[ct] - zpar[ct]*pinv;
      rz = fmaf(rv[ct], zch[ct], rz);
      rr = fmaf(rv[ct], rv[ct], rr);
    }
    rz = red16(rz); rr = red16(rr);
    float mm = rz / rr;
    float u2[8]; float uu2 = 0.f;
    #pragma unroll
    for (int ct = 0; ct < 8; ++ct){
      float z2 = fmaf(-2.0f*mm, rv[ct], zch[ct]);
      u2[ct] = z2 - a[ct];
      uu2 = fmaf(u2[ct], u2[ct], uu2);
    }
    uu2 = red16(uu2);
    float f2 = r2 / fmaxf(uu2, MINN);
    #pragma unroll
    for (int ct = 0; ct < 8; ++ct)
      zout[row*HD + ct*16 + l15] = fmaf(f2, u2[ct], a[ct]);
  }
}

// ---------------- K9: final GEMM: normalize(logmap0(z) @ fco^T + b) ----------
__global__ __launch_bounds__(64) void fin_k(const float* __restrict__ A,
    const bf16x8* __restrict__ bhi, const bf16x8* __restrict__ blo,
    const float* __restrict__ bias, float* __restrict__ out)
{
  const int lane = threadIdx.x;
  const int l15 = lane & 15, kg = lane >> 4;
  const long rb = (long)blockIdx.x*16;

  float av[4][8];
  loadA_g(A, rb, l15, kg, av);

  float ss = 0.f;
  #pragma unroll
  for (int ks = 0; ks < 4; ++ks)
    #pragma unroll
    for (int j = 0; j < 8; ++j)
      ss = fmaf(av[ks][j], av[ks][j], ss);
  ss += __shfl_xor(ss, 16, 64);
  ss += __shfl_xor(ss, 32, 64);
  float n = sqrtf(ss);
  float yn = fmaxf(n, MINN);
  float c = fminf(yn, 1.0f);
  float at = 0.5f*logf((1.0f + c)/(1.0f - c));
  float scx = at / yn;
  #pragma unroll
  for (int ks = 0; ks < 4; ++ks)
    #pragma unroll
    for (int j = 0; j < 8; ++j)
      av[ks][j] *= scx;

  f32x4 acc[8];
  mfma_core(av, bhi, blo, lane, acc);
  biasrelu(acc, bias, l15, false);

  float ss4[4] = {0.f,0.f,0.f,0.f};
  #pragma unroll
  for (int ct = 0; ct < 8; ++ct)
    #pragma unroll
    for (int q = 0; q < 4; ++q)
      ss4[q] = fmaf(acc[ct][q], acc[ct][q], ss4[q]);
  #pragma unroll
  for (int q = 0; q < 4; ++q){
    #pragma unroll
    for (int m = 1; m < 16; m <<= 1) ss4[q] += __shfl_xor(ss4[q], m, 64);
    ss4[q] = 1.0f / fmaxf(sqrtf(ss4[q]), 1e-12f);
  }
  #pragma unroll
  for (int ct = 0; ct < 8; ++ct)
    #pragma unroll
    for (int q = 0; q < 4; ++q)
      out[(rb + kg*4 + q)*HD + ct*16 + l15] = acc[ct][q]*ss4[q];
}

extern "C" void kernel_launch(void* const* d_in, const int* in_sizes, int n_in,
                              void* d_out, int out_size, void* d_ws, size_t ws_size,
                              hipStream_t stream) {
  const float* x       = (const float*)d_in[0];
  const int*   ei      = (const int*)  d_in[1];
  const float* fc0_w   = (const float*)d_in[2];
  const float* fc0_b   = (const float*)d_in[3];
  const float* w1      = (const float*)d_in[4];
  const float* b1      = (const float*)d_in[5];
  const float* gamma   = (const float*)d_in[6];
  const float* beta    = (const float*)d_in[7];
  const float* w2      = (const float*)d_in[8];
  const float* b2      = (const float*)d_in[9];
  const float* fco_w   = (const float*)d_in[10];
  const float* fco_b   = (const float*)d_in[11];
  const float* p       = (const float*)d_in[12];

  float* out = (float*)d_out;
  float* ws  = (float*)d_ws;

  float* h     = ws;                     // [NN*HD] f32
  float* zA    = h   + (size_t)NN*HD;
  float* zB    = zA  + (size_t)NN*HD;
  float* part2 = zB  + (size_t)NN*HD;    // [3][8*256] (layer-indexed, zeroed once)
  float* scale = part2 + 3*2048;         // [128]
  float* shift = scale + 128;            // [128]
  bf16x8* bhi  = (bf16x8*)(shift + 128); // [8*2048]
  bf16x8* blo  = bhi + 8*2048;           // [8*2048]
  unsigned short* hb = (unsigned short*)(blo + 8*2048); // [NN*HD] bf16 mirror
  int* cnt     = (int*)(hb + (size_t)NN*HD);
  int* ptr     = cnt + NN;               // [NN+1]
  int* fil     = ptr + NN + 1;           // [NN]
  unsigned short* eidx = (unsigned short*)(fil + NN);   // [NE] (u16 src ids)
  float* t = out;                        // reuse d_out as the w1-activation buffer

  const int* src = ei;
  const int* dst = ei + NE;
  const float scaling = tanhf(0.5f);

  // K1: weight prep + zero cnt/part2
  zero_prep_k<<<417, 64, 0, stream>>>(fc0_w, w1, w2, fco_w, bhi, blo, cnt, part2);

  // K2: fc0 tiles (h, hb, zinit->zB) + edge histogram
  fc0hist_k<<<GB + HB_BLK, 64, 0, stream>>>(x, dst, cnt, bhi, blo, fc0_b,
                                            h, hb, zB, scaling);

  // K3: merged scan; K4: fill (CSR by dst)
  scanall_k<<<NSB, 256, 0, stream>>>(cnt, ptr, fil);
  fill_k<<<512, 256, 0, stream>>>(src, dst, fil, eidx, NE);

  // ---- Layer 0 ----
  gw1_k<false,false><<<GB, 256, 0, stream>>>(
      h, bhi + 1*2048, blo + 1*2048, b1, t, part2,
      (const uint4*)hb, ptr, eidx, nullptr, nullptr, nullptr, nullptr, 0.f);
  bnfin_k<<<1, 256, 0, stream>>>(part2, gamma, beta, scale, shift);
  w2g_k<<<GB, 64, 0, stream>>>(t, bhi + 4*2048, blo + 4*2048, b2,
                               scale, shift, h, hb);      // h = h_0

  // ---- Layer 1 (gw1 carries deferred zstep_0: zc=zB, out=zA, ZFIRST) ----
  gw1_k<true,true><<<GB + ZSB, 256, 0, stream>>>(
      h, bhi + 2*2048, blo + 2*2048, b1 + HD, t, part2 + 2048,
      (const uint4*)hb, ptr, eidx, nullptr, zB, zA, p, scaling);
  bnfin_k<<<1, 256, 0, stream>>>(part2 + 2048, gamma + HD, beta + HD, scale, shift);
  w2g_k<<<GB, 64, 0, stream>>>(t, bhi + 5*2048, blo + 5*2048, b2 + HD,
                               scale, shift, h, hb);      // h = h_1

  // ---- Layer 2 (gw1 carries deferred zstep_1: zp=zB, zc=zA, out=zB) ----
  gw1_k<true,false><<<GB + ZSB, 256, 0, stream>>>(
      h, bhi + 3*2048, blo + 3*2048, b1 + 2*HD, t, part2 + 2*2048,
      (const uint4*)hb, ptr, eidx, zB, zA, zB, p, scaling);
  bnfin_k<<<1, 256, 0, stream>>>(part2 + 2*2048, gamma + 2*HD, beta + 2*HD,
                                 scale, shift);
  // w2 + fused zstep_2: zp=zA (zall_0), zc=zB (zall_1), out=zA
  w2z2_k<<<GB, 64, 0, stream>>>(t, bhi + 6*2048, blo + 6*2048, b2 + 2*HD,
                                scale, shift, zA, scaling, zA, zB, p);

  // final: out = normalize( logmap0(zA) @ fco^T + fco_b )
  fin_k<<<GB, 64, 0, stream>>>(zA, bhi + 7*2048, blo + 7*2048, fco_b, out);
}

// Round 12
// 317.763 us; speedup vs baseline: 1.0594x; 1.0594x over previous
//
#include <hip/hip_runtime.h>
#include <math.h>

#define NN 40000
#define HD 128
#define NE 640000
#define MINN 1e-15f
#define NSB 157     // ceil(NN/256) scan chunks
#define GB  2500    // 16-row tiles
#define HB_BLK 512  // hist blocks appended to fc0 dispatch

typedef __attribute__((ext_vector_type(8))) short bf16x8;
typedef __attribute__((ext_vector_type(4))) float f32x4;

__device__ __forceinline__ float red16(float v){
  v += __shfl_xor(v, 1, 64); v += __shfl_xor(v, 2, 64);
  v += __shfl_xor(v, 4, 64); v += __shfl_xor(v, 8, 64);
  return v;
}

__device__ __forceinline__ float bf2f(short h){
  return __uint_as_float(((unsigned)(unsigned short)h) << 16);
}
__device__ __forceinline__ short f2bf(float v){
  unsigned u = __float_as_uint(v);
  u += 0x7FFF + ((u >> 16) & 1);       // RNE
  return (short)(u >> 16);
}

// gather accumulate: 8 bf16 cols from one uint4 row-chunk
#define GACC(A,V) \
  A[0] += __uint_as_float((V).x << 16); A[1] += __uint_as_float((V).x & 0xffff0000u); \
  A[2] += __uint_as_float((V).y << 16); A[3] += __uint_as_float((V).y & 0xffff0000u); \
  A[4] += __uint_as_float((V).z << 16); A[5] += __uint_as_float((V).z & 0xffff0000u); \
  A[6] += __uint_as_float((V).w << 16); A[7] += __uint_as_float((V).w & 0xffff0000u);

// ---- A rows (rb+l15, cols ks*32+kg*8..+8) from global row-major [.,128] ----
__device__ __forceinline__ void loadA_g(const float* __restrict__ A, long rb,
                                        int l15, int kg, float av[4][8]){
  #pragma unroll
  for (int ks = 0; ks < 4; ++ks){
    const float* ap = A + (rb + l15)*HD + ks*32 + kg*8;
    float4 a0 = *(const float4*)ap;
    float4 a1 = *(const float4*)(ap + 4);
    av[ks][0]=a0.x; av[ks][1]=a0.y; av[ks][2]=a0.z; av[ks][3]=a0.w;
    av[ks][4]=a1.x; av[ks][5]=a1.y; av[ks][6]=a1.z; av[ks][7]=a1.w;
  }
}

// ---- split-bf16 3-term MFMA: acc = A(f32 via hi+lo) @ W^T ----
__device__ __forceinline__ void mfma_core(const float av[4][8],
    const bf16x8* __restrict__ bh, const bf16x8* __restrict__ bl,
    int lane, f32x4 acc[8]){
  #pragma unroll
  for (int ct = 0; ct < 8; ++ct){
    acc[ct][0]=0.f; acc[ct][1]=0.f; acc[ct][2]=0.f; acc[ct][3]=0.f;
  }
  #pragma unroll
  for (int ks = 0; ks < 4; ++ks){
    bf16x8 ah, al;
    #pragma unroll
    for (int j = 0; j < 8; ++j){
      float v = av[ks][j];
      short hh = f2bf(v);
      short ll = f2bf(v - bf2f(hh));
      ah[j] = hh; al[j] = ll;
    }
    #pragma unroll
    for (int ct = 0; ct < 8; ++ct){
      bf16x8 bhv = bh[(ks*8 + ct)*64 + lane];
      bf16x8 blv = bl[(ks*8 + ct)*64 + lane];
      acc[ct] = __builtin_amdgcn_mfma_f32_16x16x32_bf16(ah, bhv, acc[ct], 0, 0, 0);
      acc[ct] = __builtin_amdgcn_mfma_f32_16x16x32_bf16(al, bhv, acc[ct], 0, 0, 0);
      acc[ct] = __builtin_amdgcn_mfma_f32_16x16x32_bf16(ah, blv, acc[ct], 0, 0, 0);
    }
  }
}

__device__ __forceinline__ void biasrelu(f32x4 acc[8], const float* __restrict__ bias,
                                         int l15, bool relu){
  #pragma unroll
  for (int ct = 0; ct < 8; ++ct){
    float bb = bias[ct*16 + l15];
    #pragma unroll
    for (int q = 0; q < 4; ++q){
      float v = acc[ct][q] + bb;
      if (relu) v = fmaxf(v, 0.f);
      acc[ct][q] = v;
    }
  }
}

// ---------------- K1: weight prep (blocks 0..255) + zero cnt/part2 (blocks 256+) ----
__global__ __launch_bounds__(64) void zero_prep_k(const float* __restrict__ fc0_w,
    const float* __restrict__ w1, const float* __restrict__ w2,
    const float* __restrict__ fco_w, bf16x8* __restrict__ bhi,
    bf16x8* __restrict__ blo, int* __restrict__ cnt, float* __restrict__ part2){
  int bid = blockIdx.x;
  if (bid < 256){
    int gid = bid*64 + threadIdx.x;    // 0..16383
    int widx = gid >> 11;
    const float* W;
    if (widx == 0)      W = fc0_w;
    else if (widx <= 3) W = w1 + (size_t)(widx-1)*HD*HD;
    else if (widx <= 6) W = w2 + (size_t)(widx-4)*HD*HD;
    else                W = fco_w;
    int f  = gid & 2047;
    int ln = f & 63;
    int ct = (f >> 6) & 7;
    int ks = f >> 9;
    int n  = ct*16 + (ln & 15);
    int k0 = ks*32 + (ln >> 4)*8;
    bf16x8 hv, lv;
    #pragma unroll
    for (int j = 0; j < 8; ++j){
      float v = W[n*HD + k0 + j];
      short hh = f2bf(v);
      short ll = f2bf(v - bf2f(hh));
      hv[j] = hh; lv[j] = ll;
    }
    bhi[widx*2048 + f] = hv; blo[widx*2048 + f] = lv;
  } else {
    int i = (bid-256)*64 + threadIdx.x;
    const int st = 161*64;
    for (int j = i; j < NN; j += st) cnt[j] = 0;
    for (int j = i; j < 2048; j += st) part2[j] = 0.f;
  }
}

// ---------------- K2: fc0 tiles (blocks 0..2499) + edge histogram (blocks 2500+) ----
__global__ __launch_bounds__(64) void fc0hist_k(const float* __restrict__ x,
    const int* __restrict__ dst, int* __restrict__ cnt,
    const bf16x8* __restrict__ bhi, const bf16x8* __restrict__ blo,
    const float* __restrict__ fc0_b, float* __restrict__ h,
    unsigned short* __restrict__ hb, float* __restrict__ zB, float scaling){
  int bid = blockIdx.x;
  if (bid >= GB){
    int i = (bid - GB)*64 + threadIdx.x;
    const int st = HB_BLK*64;
    for (; i < NE; i += st) atomicAdd(&cnt[dst[i]], 1);
    return;
  }
  const int lane = threadIdx.x;
  const int l15 = lane & 15, kg = lane >> 4;
  const long rb = (long)bid*16;
  float av[4][8]; loadA_g(x, rb, l15, kg, av);
  f32x4 acc[8]; mfma_core(av, bhi, blo, lane, acc);
  biasrelu(acc, fc0_b, l15, true);
  #pragma unroll
  for (int ct = 0; ct < 8; ++ct)
    #pragma unroll
    for (int q = 0; q < 4; ++q){
      float v = acc[ct][q];
      long row = rb + kg*4 + q;
      h[row*HD + ct*16 + l15] = v;
      hb[row*HD + ct*16 + l15] = (unsigned short)f2bf(v);
    }
  #pragma unroll
  for (int q = 0; q < 4; ++q){
    float ss = 0.f;
    #pragma unroll
    for (int ct = 0; ct < 8; ++ct) ss = fmaf(acc[ct][q], acc[ct][q], ss);
    ss = red16(ss);
    float sc2 = scaling / sqrtf(ss);
    long row = rb + kg*4 + q;
    #pragma unroll
    for (int ct = 0; ct < 8; ++ct)
      zB[row*HD + ct*16 + l15] = acc[ct][q]*sc2;
  }
}

// ---------------- K3: merged full scan (R10-proven structure) ----------------
__global__ __launch_bounds__(256) void scanall_k(const int* __restrict__ cnt,
    int* __restrict__ ptr, int* __restrict__ fil){
  __shared__ int s[256];
  const int b = blockIdx.x, t = threadIdx.x;
  const int lim = b*256;
  int acc = 0;
  for (int i = t; i < lim; i += 256) acc += cnt[i];
  s[t] = acc; __syncthreads();
  for (int off = 128; off; off >>= 1){
    if (t < off) s[t] += s[t+off];
    __syncthreads();
  }
  const int pre = s[0];
  __syncthreads();
  const int idx = lim + t;
  int v = (idx < NN) ? cnt[idx] : 0;
  s[t] = v; __syncthreads();
  for (int off = 1; off < 256; off <<= 1){
    int x = (t >= off) ? s[t-off] : 0;
    __syncthreads(); s[t] += x; __syncthreads();
  }
  if (idx < NN){
    int v2 = pre + s[t] - v;
    ptr[idx] = v2; fil[idx] = v2;
  }
  if (b == NSB-1 && t == 255) ptr[NN] = pre + s[255];
}

// ---------------- K4: fill edge buckets ----------------
__global__ void fill_k(const int* __restrict__ src, const int* __restrict__ dst,
    int* __restrict__ fill, unsigned short* __restrict__ eidx, int ne){
  int i = blockIdx.x*blockDim.x + threadIdx.x;
  int st = gridDim.x*blockDim.x;
  for (; i < ne; i += st){
    int d = dst[i];
    int pos = atomicAdd(&fill[d], 1);
    eidx[pos] = (unsigned short)src[i];
  }
}

// ---------------- K5: gather + w1 GEMM, 8 waves/WG, split-edge gather ----------
// 32 lane-groups; TWO groups per node (halves of the edge list) into two LDS
// tiles — the dependent-load chain per group halves vs R6's 4-wave version.
// Wave 0 sums the tiles during its A-load and runs the verbatim R6 GEMM +
// bias/relu + atomic stats + t-write. (R8's structure minus fence/counter.)
__global__ __launch_bounds__(512) void gw1_k(const float* __restrict__ h,
    const bf16x8* __restrict__ bhi, const bf16x8* __restrict__ blo,
    const float* __restrict__ bias, float* __restrict__ t,
    float* __restrict__ part2, const uint4* __restrict__ hb4,
    const int* __restrict__ gptr, const unsigned short* __restrict__ eidx)
{
  __shared__ float tl[2*16*132];
  const int tid = threadIdx.x;
  const int lane = tid & 63;
  const int wv = tid >> 6;
  const int l15 = lane & 15, kg = lane >> 4;
  const long rb = (long)blockIdx.x*16;

  // ---- gather: group g = tid>>4; row r = g&15, half = g>>4 ----
  {
    const int g = tid >> 4;
    const int r = g & 15;
    const int half = g >> 4;
    const int l = tid & 15;
    const long node = rb + r;
    int beg = gptr[node], end = gptr[node+1];
    int mid = beg + ((end - beg) >> 1);
    int e  = half ? mid : beg;
    int e1 = half ? end : mid;
    float ga[8] = {0.f,0.f,0.f,0.f,0.f,0.f,0.f,0.f};
    if (!half){
      const float4* selfp = (const float4*)(h + node*HD) + l*2;
      float4 s0 = selfp[0], s1 = selfp[1];
      ga[0]=s0.x; ga[1]=s0.y; ga[2]=s0.z; ga[3]=s0.w;
      ga[4]=s1.x; ga[5]=s1.y; ga[6]=s1.z; ga[7]=s1.w;
    }
    for (; e + 8 <= e1; e += 8){
      int i0 = eidx[e],   i1 = eidx[e+1], i2 = eidx[e+2], i3 = eidx[e+3];
      int i4 = eidx[e+4], i5 = eidx[e+5], i6 = eidx[e+6], i7 = eidx[e+7];
      uint4 v0 = hb4[(long)i0*16 + l];
      uint4 v1 = hb4[(long)i1*16 + l];
      uint4 v2 = hb4[(long)i2*16 + l];
      uint4 v3 = hb4[(long)i3*16 + l];
      uint4 v4 = hb4[(long)i4*16 + l];
      uint4 v5 = hb4[(long)i5*16 + l];
      uint4 v6 = hb4[(long)i6*16 + l];
      uint4 v7 = hb4[(long)i7*16 + l];
      GACC(ga,v0) GACC(ga,v1) GACC(ga,v2) GACC(ga,v3)
      GACC(ga,v4) GACC(ga,v5) GACC(ga,v6) GACC(ga,v7)
    }
    if (e + 4 <= e1){
      int i0 = eidx[e], i1 = eidx[e+1], i2 = eidx[e+2], i3 = eidx[e+3];
      uint4 v0 = hb4[(long)i0*16 + l];
      uint4 v1 = hb4[(long)i1*16 + l];
      uint4 v2 = hb4[(long)i2*16 + l];
      uint4 v3 = hb4[(long)i3*16 + l];
      GACC(ga,v0) GACC(ga,v1) GACC(ga,v2) GACC(ga,v3)
      e += 4;
    }
    for (; e < e1; ++e){
      uint4 v = hb4[(long)eidx[e]*16 + l];
      GACC(ga,v)
    }
    float4* tp = (float4*)(tl + half*2112 + r*132 + l*8);
    float4 o0 = {ga[0],ga[1],ga[2],ga[3]};
    float4 o1 = {ga[4],ga[5],ga[6],ga[7]};
    tp[0] = o0; tp[1] = o1;
  }
  __syncthreads();
  if (wv != 0) return;

  // ---- wave 0: av = tlA + tlB; GEMM + bias/relu + stats + t-write ----
  float av[4][8];
  #pragma unroll
  for (int ks = 0; ks < 4; ++ks){
    const float* ap = tl + l15*132 + ks*32 + kg*8;
    float4 a0 = *(const float4*)ap;
    float4 a1 = *(const float4*)(ap + 4);
    float4 b0 = *(const float4*)(ap + 2112);
    float4 b1 = *(const float4*)(ap + 2112 + 4);
    av[ks][0]=a0.x+b0.x; av[ks][1]=a0.y+b0.y; av[ks][2]=a0.z+b0.z; av[ks][3]=a0.w+b0.w;
    av[ks][4]=a1.x+b1.x; av[ks][5]=a1.y+b1.y; av[ks][6]=a1.z+b1.z; av[ks][7]=a1.w+b1.w;
  }
  f32x4 acc[8]; mfma_core(av, bhi, blo, lane, acc);
  biasrelu(acc, bias, l15, true);

  #pragma unroll
  for (int ct = 0; ct < 8; ++ct){
    float s = 0.f, q2 = 0.f;
    #pragma unroll
    for (int q = 0; q < 4; ++q){
      float v = acc[ct][q];
      s += v; q2 = fmaf(v, v, q2);
    }
    s  += __shfl_xor(s, 16, 64);  s  += __shfl_xor(s, 32, 64);
    q2 += __shfl_xor(q2, 16, 64); q2 += __shfl_xor(q2, 32, 64);
    if (kg == 0){
      const int slot = (blockIdx.x & 7)*256;
      atomicAdd(&part2[slot + ct*16 + l15], s);
      atomicAdd(&part2[slot + 128 + ct*16 + l15], q2);
    }
  }

  #pragma unroll
  for (int ct = 0; ct < 8; ++ct)
    #pragma unroll
    for (int q = 0; q < 4; ++q)
      t[(rb + kg*4 + q)*HD + ct*16 + l15] = acc[ct][q];
}

// ---------------- MFMA GEMM with fused pre/post ops (1 wave/block; R6 verbatim) ----
template<bool RELU, bool BN_IN, bool XH_IN, bool NORM_OUT,
         bool WRITE_HB, bool WRITE_OUT, bool ZSTEP, bool ZFIRST>
__global__ __launch_bounds__(64) void mgemm_k(const float* __restrict__ A,
    const bf16x8* __restrict__ bhi, const bf16x8* __restrict__ blo,
    const float* __restrict__ bias, const float* __restrict__ scale,
    const float* __restrict__ shift, float* __restrict__ out,
    unsigned short* __restrict__ hbout, float* __restrict__ zout, float scaling,
    const float* __restrict__ zpin, const float* __restrict__ zcin,
    const float* __restrict__ pvec)
{
  const int lane = threadIdx.x;
  const int l15 = lane & 15, kg = lane >> 4;
  const long rb = (long)blockIdx.x*16;   // 2500*16 = 40000 exact

  float av[4][8];
  loadA_g(A, rb, l15, kg, av);

  // ---- ZSTEP operand prefetch (issued before the MFMA stream; consumed after) ----
  float zc_a[4][8], zp_a[4][8], pvr[8];
  if constexpr (ZSTEP){
    #pragma unroll
    for (int q = 0; q < 4; ++q){
      const long row = rb + kg*4 + q;
      #pragma unroll
      for (int ct = 0; ct < 8; ++ct)
        zc_a[q][ct] = zcin[row*HD + ct*16 + l15];
    }
    if constexpr (!ZFIRST){
      #pragma unroll
      for (int q = 0; q < 4; ++q){
        const long row = rb + kg*4 + q;
        #pragma unroll
        for (int ct = 0; ct < 8; ++ct)
          zp_a[q][ct] = zpin[row*HD + ct*16 + l15];
      }
    }
    #pragma unroll
    for (int ct = 0; ct < 8; ++ct) pvr[ct] = pvec[ct*16 + l15];
  }

  if (BN_IN){
    #pragma unroll
    for (int ks = 0; ks < 4; ++ks){
      const int k0 = ks*32 + kg*8;
      float4 s0 = *(const float4*)(scale + k0);
      float4 s1 = *(const float4*)(scale + k0 + 4);
      float4 h0 = *(const float4*)(shift + k0);
      float4 h1 = *(const float4*)(shift + k0 + 4);
      float sc[8] = {s0.x,s0.y,s0.z,s0.w,s1.x,s1.y,s1.z,s1.w};
      float sh[8] = {h0.x,h0.y,h0.z,h0.w,h1.x,h1.y,h1.z,h1.w};
      #pragma unroll
      for (int j = 0; j < 8; ++j)
        av[ks][j] = fmaf(av[ks][j], sc[j], sh[j]);
    }
  }
  if (XH_IN){
    float ss = 0.f;
    #pragma unroll
    for (int ks = 0; ks < 4; ++ks)
      #pragma unroll
      for (int j = 0; j < 8; ++j)
        ss = fmaf(av[ks][j], av[ks][j], ss);
    ss += __shfl_xor(ss, 16, 64);
    ss += __shfl_xor(ss, 32, 64);
    float n = sqrtf(ss);
    float yn = fmaxf(n, MINN);
    float c = fminf(yn, 1.0f);
    float at = 0.5f*logf((1.0f + c)/(1.0f - c));
    float scx = at / yn;
    #pragma unroll
    for (int ks = 0; ks < 4; ++ks)
      #pragma unroll
      for (int j = 0; j < 8; ++j)
        av[ks][j] *= scx;
  }

  f32x4 acc[8];
  mfma_core(av, bhi, blo, lane, acc);
  biasrelu(acc, bias, l15, RELU);

  if (NORM_OUT){
    float ss[4] = {0.f,0.f,0.f,0.f};
    #pragma unroll
    for (int ct = 0; ct < 8; ++ct)
      #pragma unroll
      for (int q = 0; q < 4; ++q)
        ss[q] = fmaf(acc[ct][q], acc[ct][q], ss[q]);
    #pragma unroll
    for (int q = 0; q < 4; ++q){
      #pragma unroll
      for (int m = 1; m < 16; m <<= 1) ss[q] += __shfl_xor(ss[q], m, 64);
      ss[q] = 1.0f / fmaxf(sqrtf(ss[q]), 1e-12f);
    }
    #pragma unroll
    for (int ct = 0; ct < 8; ++ct)
      #pragma unroll
      for (int q = 0; q < 4; ++q)
        acc[ct][q] *= ss[q];
  }

  if constexpr (ZSTEP){
    // q_ = p/|p| is row-independent
    float pq = 0.f;
    #pragma unroll
    for (int ct = 0; ct < 8; ++ct) pq = fmaf(pvr[ct], pvr[ct], pq);
    pq = red16(pq);
    float qi = 1.0f / fmaxf(sqrtf(pq), MINN);
    #pragma unroll
    for (int ct = 0; ct < 8; ++ct) pvr[ct] *= qi;

    #pragma unroll
    for (int q = 0; q < 4; ++q){
      const long row = rb + kg*4 + q;
      float zc[8], zp[8];
      #pragma unroll
      for (int ct = 0; ct < 8; ++ct) zc[ct] = zc_a[q][ct];
      if constexpr (!ZFIRST){
        #pragma unroll
        for (int ct = 0; ct < 8; ++ct) zp[ct] = zp_a[q][ct];
      } else {
        #pragma unroll
        for (int ct = 0; ct < 8; ++ct) zp[ct] = 0.f;
      }
      float hh = 0.f, cc = 0.f;
      #pragma unroll
      for (int ct = 0; ct < 8; ++ct){
        hh = fmaf(acc[ct][q], acc[ct][q], hh);
        cc = fmaf(zc[ct], zc[ct], cc);
      }
      hh = red16(hh); cc = red16(cc);
      float zs = scaling / sqrtf(hh);
      float di = 1.0f / fmaxf(cc, MINN);
      float r2 = cc*di*di - 1.0f;
      float a[8], u[8]; float uu = 0.f;
      #pragma unroll
      for (int ct = 0; ct < 8; ++ct){
        a[ct] = zc[ct]*di;
        u[ct] = zp[ct] - a[ct];
        uu = fmaf(u[ct], u[ct], uu);
      }
      uu = red16(uu);
      float f = r2 / fmaxf(uu, MINN);
      float zpar[8]; float pn2 = 0.f;
      #pragma unroll
      for (int ct = 0; ct < 8; ++ct){
        zpar[ct] = fmaf(f, u[ct], a[ct]);
        pn2 = fmaf(zpar[ct], zpar[ct], pn2);
      }
      pn2 = red16(pn2);
      float pinv = 1.0f / fmaxf(sqrtf(pn2), MINN);
      float rv[8], zch[8]; float rz = 0.f, rr = 0.f;
      #pragma unroll
      for (int ct = 0; ct < 8; ++ct){
        zch[ct] = acc[ct][q]*zs;
        rv[ct] = pvr[ct] - zpar[ct]*pinv;
        rz = fmaf(rv[ct], zch[ct], rz);
        rr = fmaf(rv[ct], rv[ct], rr);
      }
      rz = red16(rz); rr = red16(rr);
      float mm = rz / rr;
      float u2[8]; float uu2 = 0.f;
      #pragma unroll
      for (int ct = 0; ct < 8; ++ct){
        float z2 = fmaf(-2.0f*mm, rv[ct], zch[ct]);
        u2[ct] = z2 - a[ct];
        uu2 = fmaf(u2[ct], u2[ct], uu2);
      }
      uu2 = red16(uu2);
      float f2 = r2 / fmaxf(uu2, MINN);
      #pragma unroll
      for (int ct = 0; ct < 8; ++ct)
        zout[row*HD + ct*16 + l15] = fmaf(f2, u2[ct], a[ct]);
    }
  }

  if constexpr (WRITE_OUT || WRITE_HB){
    #pragma unroll
    for (int ct = 0; ct < 8; ++ct)
      #pragma unroll
      for (int q = 0; q < 4; ++q){
        float v = acc[ct][q];
        long row = rb + kg*4 + q;
        if (WRITE_OUT) out[row*HD + ct*16 + l15] = v;
        if (WRITE_HB) hbout[row*HD + ct*16 + l15] = (unsigned short)f2bf(v);
      }
  }
}

// ---------------- BN finalize: part2[8][256] -> scale/shift; re-zero part2 ----------
__global__ __launch_bounds__(256) void bnfin_k(float* __restrict__ part2,
    const float* __restrict__ g, const float* __restrict__ b,
    float* __restrict__ scale, float* __restrict__ shift){
  __shared__ float sm[256];
  float tot = 0.f;
  #pragma unroll
  for (int r = 0; r < 8; ++r) tot += part2[r*256 + threadIdx.x];
  sm[threadIdx.x] = tot;
  __syncthreads();
  if (threadIdx.x < 128){
    int c = threadIdx.x;
    float s = sm[c], q = sm[c + 128];
    float mu  = s * (1.0f/NN);
    float var = q * (1.0f/NN) - mu*mu;
    float istd = rsqrtf(var + 1e-5f);
    float scv = g[c]*istd;
    scale[c] = scv;
    shift[c] = fmaf(-mu, scv, b[c]);
  }
  #pragma unroll
  for (int r = 0; r < 8; ++r) part2[r*256 + threadIdx.x] = 0.f;
}

extern "C" void kernel_launch(void* const* d_in, const int* in_sizes, int n_in,
                              void* d_out, int out_size, void* d_ws, size_t ws_size,
                              hipStream_t stream) {
  const float* x       = (const float*)d_in[0];
  const int*   ei      = (const int*)  d_in[1];
  const float* fc0_w   = (const float*)d_in[2];
  const float* fc0_b   = (const float*)d_in[3];
  const float* w1      = (const float*)d_in[4];
  const float* b1      = (const float*)d_in[5];
  const float* gamma   = (const float*)d_in[6];
  const float* beta    = (const float*)d_in[7];
  const float* w2      = (const float*)d_in[8];
  const float* b2      = (const float*)d_in[9];
  const float* fco_w   = (const float*)d_in[10];
  const float* fco_b   = (const float*)d_in[11];
  const float* p       = (const float*)d_in[12];

  float* out = (float*)d_out;
  float* ws  = (float*)d_ws;

  float* h     = ws;                     // [NN*HD] f32
  float* zA    = h   + (size_t)NN*HD;
  float* zB    = zA  + (size_t)NN*HD;
  float* part2 = zB  + (size_t)NN*HD;    // [8*256]
  float* scale = part2 + 8*256;          // [128]
  float* shift = scale + 128;            // [128]
  bf16x8* bhi  = (bf16x8*)(shift + 128); // [8*2048]
  bf16x8* blo  = bhi + 8*2048;           // [8*2048]
  unsigned short* hb = (unsigned short*)(blo + 8*2048); // [NN*HD] bf16 mirror
  int* cnt     = (int*)(hb + (size_t)NN*HD);
  int* ptr     = cnt + NN;               // [NN+1]
  int* fil     = ptr + NN + 1;           // [NN]
  unsigned short* eidx = (unsigned short*)(fil + NN);   // [NE] (u16 src ids)
  float* t = out;                        // reuse d_out as the w1-activation buffer

  const int* src = ei;
  const int* dst = ei + NE;
  const float scaling = tanhf(0.5f);

  // K1: weight prep + zero cnt/part2
  zero_prep_k<<<417, 64, 0, stream>>>(fc0_w, w1, w2, fco_w, bhi, blo, cnt, part2);

  // K2: fc0 tiles (h, hb, zinit->zB) + edge histogram
  fc0hist_k<<<GB + HB_BLK, 64, 0, stream>>>(x, dst, cnt, bhi, blo, fc0_b,
                                            h, hb, zB, scaling);

  // K3: merged scan; K4: fill (CSR by dst)
  scanall_k<<<NSB, 256, 0, stream>>>(cnt, ptr, fil);
  fill_k<<<512, 256, 0, stream>>>(src, dst, fil, eidx, NE);

  float* zprev = zA; float* zcur = zB;

  for (int i = 0; i < 3; ++i) {
    // t = relu((h + agg(h)) @ w1^T + b1); 8-wave split-edge gather; stats -> part2
    gw1_k<<<GB, 512, 0, stream>>>(
        h, bhi + (1+i)*2048, blo + (1+i)*2048, b1 + i*HD, t, part2,
        (const uint4*)hb, ptr, eidx);
    bnfin_k<<<1, 256, 0, stream>>>(part2, gamma + i*HD, beta + i*HD, scale, shift);
    // h = relu( BN(t) @ w2^T + b2 ) + fused hyperbolic z-step (R6 verbatim).
    if (i == 0)
      mgemm_k<true,true,false,false,true,true,true,true>
          <<<GB, 64, 0, stream>>>(
          t, bhi + 4*2048, blo + 4*2048, b2, scale, shift, h, hb,
          zprev, scaling, zprev, zcur, p);
    else if (i == 1)
      mgemm_k<true,true,false,false,true,true,true,false>
          <<<GB, 64, 0, stream>>>(
          t, bhi + 5*2048, blo + 5*2048, b2 + HD, scale, shift, h, hb,
          zprev, scaling, zprev, zcur, p);
    else
      mgemm_k<true,true,false,false,false,false,true,false>
          <<<GB, 64, 0, stream>>>(
          t, bhi + 6*2048, blo + 6*2048, b2 + 2*HD, scale, shift, h, nullptr,
          zprev, scaling, zprev, zcur, p);
    float* tmp = zprev; zprev = zcur; zcur = tmp;
  }

  // out = normalize( logmap0(z_cur) @ fc_out^T + fc_out_b )
  mgemm_k<false,false,true,true,false,true,false,false>
      <<<GB, 64, 0, stream>>>(
      zcur, bhi + 7*2048, blo + 7*2048, fco_b, nullptr, nullptr, out,
      nullptr, nullptr, 0.f, nullptr, nullptr, nullptr);
}

// Round 13
// 294.811 us; speedup vs baseline: 1.1419x; 1.0779x over previous
//
#include <hip/hip_runtime.h>
#include <math.h>

#define NN 40000
#define HD 128
#define NE 640000
#define MINN 1e-15f
#define NSB 157     // ceil(NN/256) scan chunks
#define GB  2500    // 16-row tiles
#define HB_BLK 512  // hist blocks appended to fc0 dispatch

typedef __attribute__((ext_vector_type(8))) short bf16x8;
typedef __attribute__((ext_vector_type(4))) float f32x4;

__device__ __forceinline__ float red16(float v){
  v += __shfl_xor(v, 1, 64); v += __shfl_xor(v, 2, 64);
  v += __shfl_xor(v, 4, 64); v += __shfl_xor(v, 8, 64);
  return v;
}

__device__ __forceinline__ float bf2f(short h){
  return __uint_as_float(((unsigned)(unsigned short)h) << 16);
}
__device__ __forceinline__ short f2bf(float v){
  unsigned u = __float_as_uint(v);
  u += 0x7FFF + ((u >> 16) & 1);       // RNE
  return (short)(u >> 16);
}

// gather accumulate: 8 bf16 cols from one uint4 row-chunk
#define GACC(A,V) \
  A[0] += __uint_as_float((V).x << 16); A[1] += __uint_as_float((V).x & 0xffff0000u); \
  A[2] += __uint_as_float((V).y << 16); A[3] += __uint_as_float((V).y & 0xffff0000u); \
  A[4] += __uint_as_float((V).z << 16); A[5] += __uint_as_float((V).z & 0xffff0000u); \
  A[6] += __uint_as_float((V).w << 16); A[7] += __uint_as_float((V).w & 0xffff0000u);

// ---- A rows (rb+l15, cols ks*32+kg*8..+8) from global row-major [.,128] ----
__device__ __forceinline__ void loadA_g(const float* __restrict__ A, long rb,
                                        int l15, int kg, float av[4][8]){
  #pragma unroll
  for (int ks = 0; ks < 4; ++ks){
    const float* ap = A + (rb + l15)*HD + ks*32 + kg*8;
    float4 a0 = *(const float4*)ap;
    float4 a1 = *(const float4*)(ap + 4);
    av[ks][0]=a0.x; av[ks][1]=a0.y; av[ks][2]=a0.z; av[ks][3]=a0.w;
    av[ks][4]=a1.x; av[ks][5]=a1.y; av[ks][6]=a1.z; av[ks][7]=a1.w;
  }
}

// ---- split-bf16 3-term MFMA: acc = A(f32 via hi+lo) @ W^T ----
__device__ __forceinline__ void mfma_core(const float av[4][8],
    const bf16x8* __restrict__ bh, const bf16x8* __restrict__ bl,
    int lane, f32x4 acc[8]){
  #pragma unroll
  for (int ct = 0; ct < 8; ++ct){
    acc[ct][0]=0.f; acc[ct][1]=0.f; acc[ct][2]=0.f; acc[ct][3]=0.f;
  }
  #pragma unroll
  for (int ks = 0; ks < 4; ++ks){
    bf16x8 ah, al;
    #pragma unroll
    for (int j = 0; j < 8; ++j){
      float v = av[ks][j];
      short hh = f2bf(v);
      short ll = f2bf(v - bf2f(hh));
      ah[j] = hh; al[j] = ll;
    }
    #pragma unroll
    for (int ct = 0; ct < 8; ++ct){
      bf16x8 bhv = bh[(ks*8 + ct)*64 + lane];
      bf16x8 blv = bl[(ks*8 + ct)*64 + lane];
      acc[ct] = __builtin_amdgcn_mfma_f32_16x16x32_bf16(ah, bhv, acc[ct], 0, 0, 0);
      acc[ct] = __builtin_amdgcn_mfma_f32_16x16x32_bf16(al, bhv, acc[ct], 0, 0, 0);
      acc[ct] = __builtin_amdgcn_mfma_f32_16x16x32_bf16(ah, blv, acc[ct], 0, 0, 0);
    }
  }
}

__device__ __forceinline__ void biasrelu(f32x4 acc[8], const float* __restrict__ bias,
                                         int l15, bool relu){
  #pragma unroll
  for (int ct = 0; ct < 8; ++ct){
    float bb = bias[ct*16 + l15];
    #pragma unroll
    for (int q = 0; q < 4; ++q){
      float v = acc[ct][q] + bb;
      if (relu) v = fmaxf(v, 0.f);
      acc[ct][q] = v;
    }
  }
}

// ---------------- K1: weight prep (blocks 0..255) + zero cnt/part2 (blocks 256+) ----
__global__ __launch_bounds__(64) void zero_prep_k(const float* __restrict__ fc0_w,
    const float* __restrict__ w1, const float* __restrict__ w2,
    const float* __restrict__ fco_w, bf16x8* __restrict__ bhi,
    bf16x8* __restrict__ blo, int* __restrict__ cnt, float* __restrict__ part2){
  int bid = blockIdx.x;
  if (bid < 256){
    int gid = bid*64 + threadIdx.x;    // 0..16383
    int widx = gid >> 11;
    const float* W;
    if (widx == 0)      W = fc0_w;
    else if (widx <= 3) W = w1 + (size_t)(widx-1)*HD*HD;
    else if (widx <= 6) W = w2 + (size_t)(widx-4)*HD*HD;
    else                W = fco_w;
    int f  = gid & 2047;
    int ln = f & 63;
    int ct = (f >> 6) & 7;
    int ks = f >> 9;
    int n  = ct*16 + (ln & 15);
    int k0 = ks*32 + (ln >> 4)*8;
    bf16x8 hv, lv;
    #pragma unroll
    for (int j = 0; j < 8; ++j){
      float v = W[n*HD + k0 + j];
      short hh = f2bf(v);
      short ll = f2bf(v - bf2f(hh));
      hv[j] = hh; lv[j] = ll;
    }
    bhi[widx*2048 + f] = hv; blo[widx*2048 + f] = lv;
  } else {
    int i = (bid-256)*64 + threadIdx.x;
    const int st = 161*64;
    for (int j = i; j < NN; j += st) cnt[j] = 0;
    for (int j = i; j < 2048; j += st) part2[j] = 0.f;
  }
}

// ---------------- K2: fc0 tiles (blocks 0..2499) + edge histogram (blocks 2500+) ----
__global__ __launch_bounds__(64) void fc0hist_k(const float* __restrict__ x,
    const int* __restrict__ dst, int* __restrict__ cnt,
    const bf16x8* __restrict__ bhi, const bf16x8* __restrict__ blo,
    const float* __restrict__ fc0_b, float* __restrict__ h,
    unsigned short* __restrict__ hb, float* __restrict__ zB, float scaling){
  int bid = blockIdx.x;
  if (bid >= GB){
    int i = (bid - GB)*64 + threadIdx.x;
    const int st = HB_BLK*64;
    for (; i < NE; i += st) atomicAdd(&cnt[dst[i]], 1);
    return;
  }
  const int lane = threadIdx.x;
  const int l15 = lane & 15, kg = lane >> 4;
  const long rb = (long)bid*16;
  float av[4][8]; loadA_g(x, rb, l15, kg, av);
  f32x4 acc[8]; mfma_core(av, bhi, blo, lane, acc);
  biasrelu(acc, fc0_b, l15, true);
  #pragma unroll
  for (int ct = 0; ct < 8; ++ct)
    #pragma unroll
    for (int q = 0; q < 4; ++q){
      float v = acc[ct][q];
      long row = rb + kg*4 + q;
      h[row*HD + ct*16 + l15] = v;
      hb[row*HD + ct*16 + l15] = (unsigned short)f2bf(v);
    }
  #pragma unroll
  for (int q = 0; q < 4; ++q){
    float ss = 0.f;
    #pragma unroll
    for (int ct = 0; ct < 8; ++ct) ss = fmaf(acc[ct][q], acc[ct][q], ss);
    ss = red16(ss);
    float sc2 = scaling / sqrtf(ss);
    long row = rb + kg*4 + q;
    #pragma unroll
    for (int ct = 0; ct < 8; ++ct)
      zB[row*HD + ct*16 + l15] = acc[ct][q]*sc2;
  }
}

// ---------------- K3: per-chunk inclusive scan ----------------
__global__ __launch_bounds__(256) void scan1_k(const int* __restrict__ cnt,
    int* __restrict__ locpre, int* __restrict__ btot){
  __shared__ int s[256];
  int t = threadIdx.x;
  int idx = blockIdx.x*256 + t;
  int v = (idx < NN) ? cnt[idx] : 0;
  s[t] = v; __syncthreads();
  for (int off = 1; off < 256; off <<= 1){
    int x = (t >= off) ? s[t-off] : 0;
    __syncthreads(); s[t] += x; __syncthreads();
  }
  locpre[idx] = s[t] - v;
  if (t == 255) btot[blockIdx.x] = s[255];
}

// ---------------- K4: merged scan2+scan3 (each block redundantly scans btot) ----
__global__ __launch_bounds__(256) void scan23_k(const int* __restrict__ btot,
    const int* __restrict__ locpre, int* __restrict__ ptr, int* __restrict__ fil){
  __shared__ int s[256];
  int t = threadIdx.x;
  int v = (t < NSB) ? btot[t] : 0;
  s[t] = v; __syncthreads();
  for (int off = 1; off < 256; off <<= 1){
    int x = (t >= off) ? s[t-off] : 0;
    __syncthreads(); s[t] += x; __syncthreads();
  }
  int bid = blockIdx.x;
  int pre = (bid == 0) ? 0 : s[bid-1];
  int idx = bid*256 + t;
  if (idx < NN){
    int v2 = pre + locpre[idx];
    ptr[idx] = v2; fil[idx] = v2;
  }
  if (bid == 0 && t == 0) ptr[NN] = s[NSB-1];
}

// ---------------- K5: fill edge buckets ----------------
__global__ void fill_k(const int* __restrict__ src, const int* __restrict__ dst,
    int* __restrict__ fill, unsigned short* __restrict__ eidx, int ne){
  int i = blockIdx.x*blockDim.x + threadIdx.x;
  int st = gridDim.x*blockDim.x;
  for (; i < ne; i += st){
    int d = dst[i];
    int pos = atomicAdd(&fill[d], 1);
    eidx[pos] = (unsigned short)src[i];
  }
}

// ---------------- K6: gather + w1 GEMM, 4 waves/WG ----------------
// Waves 0-3: each of the 16 lane-groups gathers ONE node into the shared
// 16x132 LDS tile. After the barrier wave 0 alone runs the proven 16x128
// GEMM + bias/relu + atomic stats + t-write.
__global__ __launch_bounds__(256) void gw1_k(const float* __restrict__ h,
    const bf16x8* __restrict__ bhi, const bf16x8* __restrict__ blo,
    const float* __restrict__ bias, float* __restrict__ t,
    float* __restrict__ part2, const uint4* __restrict__ hb4,
    const int* __restrict__ gptr, const unsigned short* __restrict__ eidx)
{
  __shared__ float tl[16*132];
  const int tid = threadIdx.x;
  const int lane = tid & 63;
  const int wv = tid >> 6;
  const int l15 = lane & 15, kg = lane >> 4;
  const long rb = (long)blockIdx.x*16;

  // ---- gather: lane-group (wv,kg) owns tile row r = wv*4+kg ----
  {
    const int r = wv*4 + kg;
    const long node = rb + r;
    int beg = gptr[node], end = gptr[node+1];
    const float4* selfp = (const float4*)(h + node*HD) + l15*2;
    float4 s0 = selfp[0], s1 = selfp[1];
    float ga[8] = {s0.x,s0.y,s0.z,s0.w,s1.x,s1.y,s1.z,s1.w};
    int e = beg;
    for (; e + 8 <= end; e += 8){
      int i0 = eidx[e],   i1 = eidx[e+1], i2 = eidx[e+2], i3 = eidx[e+3];
      int i4 = eidx[e+4], i5 = eidx[e+5], i6 = eidx[e+6], i7 = eidx[e+7];
      uint4 v0 = hb4[(long)i0*16 + l15];
      uint4 v1 = hb4[(long)i1*16 + l15];
      uint4 v2 = hb4[(long)i2*16 + l15];
      uint4 v3 = hb4[(long)i3*16 + l15];
      uint4 v4 = hb4[(long)i4*16 + l15];
      uint4 v5 = hb4[(long)i5*16 + l15];
      uint4 v6 = hb4[(long)i6*16 + l15];
      uint4 v7 = hb4[(long)i7*16 + l15];
      GACC(ga,v0) GACC(ga,v1) GACC(ga,v2) GACC(ga,v3)
      GACC(ga,v4) GACC(ga,v5) GACC(ga,v6) GACC(ga,v7)
    }
    if (e + 4 <= end){
      int i0 = eidx[e], i1 = eidx[e+1], i2 = eidx[e+2], i3 = eidx[e+3];
      uint4 v0 = hb4[(long)i0*16 + l15];
      uint4 v1 = hb4[(long)i1*16 + l15];
      uint4 v2 = hb4[(long)i2*16 + l15];
      uint4 v3 = hb4[(long)i3*16 + l15];
      GACC(ga,v0) GACC(ga,v1) GACC(ga,v2) GACC(ga,v3)
      e += 4;
    }
    for (; e < end; ++e){
      uint4 v = hb4[(long)eidx[e]*16 + l15];
      GACC(ga,v)
    }
    float4* tp = (float4*)(tl + r*132 + l15*8);
    float4 o0 = {ga[0],ga[1],ga[2],ga[3]};
    float4 o1 = {ga[4],ga[5],ga[6],ga[7]};
    tp[0] = o0; tp[1] = o1;
  }
  __syncthreads();
  if (wv != 0) return;

  // ---- wave 0: GEMM + bias/relu + stats + t-write ----
  float av[4][8];
  #pragma unroll
  for (int ks = 0; ks < 4; ++ks){
    const float* ap = tl + l15*132 + ks*32 + kg*8;
    float4 a0 = *(const float4*)ap;
    float4 a1 = *(const float4*)(ap + 4);
    av[ks][0]=a0.x; av[ks][1]=a0.y; av[ks][2]=a0.z; av[ks][3]=a0.w;
    av[ks][4]=a1.x; av[ks][5]=a1.y; av[ks][6]=a1.z; av[ks][7]=a1.w;
  }
  f32x4 acc[8]; mfma_core(av, bhi, blo, lane, acc);
  biasrelu(acc, bias, l15, true);

  #pragma unroll
  for (int ct = 0; ct < 8; ++ct){
    float s = 0.f, q2 = 0.f;
    #pragma unroll
    for (int q = 0; q < 4; ++q){
      float v = acc[ct][q];
      s += v; q2 = fmaf(v, v, q2);
    }
    s  += __shfl_xor(s, 16, 64);  s  += __shfl_xor(s, 32, 64);
    q2 += __shfl_xor(q2, 16, 64); q2 += __shfl_xor(q2, 32, 64);
    if (kg == 0){
      const int slot = (blockIdx.x & 7)*256;
      atomicAdd(&part2[slot + ct*16 + l15], s);
      atomicAdd(&part2[slot + 128 + ct*16 + l15], q2);
    }
  }

  #pragma unroll
  for (int ct = 0; ct < 8; ++ct)
    #pragma unroll
    for (int q = 0; q < 4; ++q)
      t[(rb + kg*4 + q)*HD + ct*16 + l15] = acc[ct][q];
}

// ---------------- MFMA GEMM with fused pre/post ops (1 wave/block) ----------------
// ZSTEP: zc/zp/p loads hoisted BEFORE the MFMA stream (latency overlap).
template<bool RELU, bool BN_IN, bool XH_IN, bool NORM_OUT,
         bool WRITE_HB, bool WRITE_OUT, bool ZSTEP, bool ZFIRST>
__global__ __launch_bounds__(64) void mgemm_k(const float* __restrict__ A,
    const bf16x8* __restrict__ bhi, const bf16x8* __restrict__ blo,
    const float* __restrict__ bias, const float* __restrict__ scale,
    const float* __restrict__ shift, float* __restrict__ out,
    unsigned short* __restrict__ hbout, float* __restrict__ zout, float scaling,
    const float* __restrict__ zpin, const float* __restrict__ zcin,
    const float* __restrict__ pvec)
{
  const int lane = threadIdx.x;
  const int l15 = lane & 15, kg = lane >> 4;
  const long rb = (long)blockIdx.x*16;   // 2500*16 = 40000 exact

  float av[4][8];
  loadA_g(A, rb, l15, kg, av);

  // ---- ZSTEP operand prefetch (issued before the MFMA stream; consumed after) ----
  float zc_a[4][8], zp_a[4][8], pvr[8];
  if constexpr (ZSTEP){
    #pragma unroll
    for (int q = 0; q < 4; ++q){
      const long row = rb + kg*4 + q;
      #pragma unroll
      for (int ct = 0; ct < 8; ++ct)
        zc_a[q][ct] = zcin[row*HD + ct*16 + l15];
    }
    if constexpr (!ZFIRST){
      #pragma unroll
      for (int q = 0; q < 4; ++q){
        const long row = rb + kg*4 + q;
        #pragma unroll
        for (int ct = 0; ct < 8; ++ct)
          zp_a[q][ct] = zpin[row*HD + ct*16 + l15];
      }
    }
    #pragma unroll
    for (int ct = 0; ct < 8; ++ct) pvr[ct] = pvec[ct*16 + l15];
  }

  if (BN_IN){
    #pragma unroll
    for (int ks = 0; ks < 4; ++ks){
      const int k0 = ks*32 + kg*8;
      float4 s0 = *(const float4*)(scale + k0);
      float4 s1 = *(const float4*)(scale + k0 + 4);
      float4 h0 = *(const float4*)(shift + k0);
      float4 h1 = *(const float4*)(shift + k0 + 4);
      float sc[8] = {s0.x,s0.y,s0.z,s0.w,s1.x,s1.y,s1.z,s1.w};
      float sh[8] = {h0.x,h0.y,h0.z,h0.w,h1.x,h1.y,h1.z,h1.w};
      #pragma unroll
      for (int j = 0; j < 8; ++j)
        av[ks][j] = fmaf(av[ks][j], sc[j], sh[j]);
    }
  }
  if (XH_IN){
    float ss = 0.f;
    #pragma unroll
    for (int ks = 0; ks < 4; ++ks)
      #pragma unroll
      for (int j = 0; j < 8; ++j)
        ss = fmaf(av[ks][j], av[ks][j], ss);
    ss += __shfl_xor(ss, 16, 64);
    ss += __shfl_xor(ss, 32, 64);
    float n = sqrtf(ss);
    float yn = fmaxf(n, MINN);
    float c = fminf(yn, 1.0f);
    float at = 0.5f*logf((1.0f + c)/(1.0f - c));
    float scx = at / yn;
    #pragma unroll
    for (int ks = 0; ks < 4; ++ks)
      #pragma unroll
      for (int j = 0; j < 8; ++j)
        av[ks][j] *= scx;
  }

  f32x4 acc[8];
  mfma_core(av, bhi, blo, lane, acc);
  biasrelu(acc, bias, l15, RELU);

  if (NORM_OUT){
    float ss[4] = {0.f,0.f,0.f,0.f};
    #pragma unroll
    for (int ct = 0; ct < 8; ++ct)
      #pragma unroll
      for (int q = 0; q < 4; ++q)
        ss[q] = fmaf(acc[ct][q], acc[ct][q], ss[q]);
    #pragma unroll
    for (int q = 0; q < 4; ++q){
      #pragma unroll
      for (int m = 1; m < 16; m <<= 1) ss[q] += __shfl_xor(ss[q], m, 64);
      ss[q] = 1.0f / fmaxf(sqrtf(ss[q]), 1e-12f);
    }
    #pragma unroll
    for (int ct = 0; ct < 8; ++ct)
      #pragma unroll
      for (int q = 0; q < 4; ++q)
        acc[ct][q] *= ss[q];
  }

  if constexpr (ZSTEP){
    // q_ = p/|p| is row-independent
    float pq = 0.f;
    #pragma unroll
    for (int ct = 0; ct < 8; ++ct) pq = fmaf(pvr[ct], pvr[ct], pq);
    pq = red16(pq);
    float qi = 1.0f / fmaxf(sqrtf(pq), MINN);
    #pragma unroll
    for (int ct = 0; ct < 8; ++ct) pvr[ct] *= qi;

    #pragma unroll
    for (int q = 0; q < 4; ++q){
      const long row = rb + kg*4 + q;
      float zc[8], zp[8];
      #pragma unroll
      for (int ct = 0; ct < 8; ++ct) zc[ct] = zc_a[q][ct];
      if constexpr (!ZFIRST){
        #pragma unroll
        for (int ct = 0; ct < 8; ++ct) zp[ct] = zp_a[q][ct];
      } else {
        #pragma unroll
        for (int ct = 0; ct < 8; ++ct) zp[ct] = 0.f;
      }
      float hh = 0.f, cc = 0.f;
      #pragma unroll
      for (int ct = 0; ct < 8; ++ct){
        hh = fmaf(acc[ct][q], acc[ct][q], hh);
        cc = fmaf(zc[ct], zc[ct], cc);
      }
      hh = red16(hh); cc = red16(cc);
      float zs = scaling / sqrtf(hh);
      float di = 1.0f / fmaxf(cc, MINN);
      float r2 = cc*di*di - 1.0f;
      float a[8], u[8]; float uu = 0.f;
      #pragma unroll
      for (int ct = 0; ct < 8; ++ct){
        a[ct] = zc[ct]*di;
        u[ct] = zp[ct] - a[ct];
        uu = fmaf(u[ct], u[ct], uu);
      }
      uu = red16(uu);
      float f = r2 / fmaxf(uu, MINN);
      float zpar[8]; float pn2 = 0.f;
      #pragma unroll
      for (int ct = 0; ct < 8; ++ct){
        zpar[ct] = fmaf(f, u[ct], a[ct]);
        pn2 = fmaf(zpar[ct], zpar[ct], pn2);
      }
      pn2 = red16(pn2);
      float pinv = 1.0f / fmaxf(sqrtf(pn2), MINN);
      float rv[8], zch[8]; float rz = 0.f, rr = 0.f;
      #pragma unroll
      for (int ct = 0; ct < 8; ++ct){
        zch[ct] = acc[ct][q]*zs;
        rv[ct] = pvr[ct] - zpar[ct]*pinv;
        rz = fmaf(rv[ct], zch[ct], rz);
        rr = fmaf(rv[ct], rv[ct], rr);
      }
      rz = red16(rz); rr = red16(rr);
      float mm = rz / rr;
      float u2[8]; float uu2 = 0.f;
      #pragma unroll
      for (int ct = 0; ct < 8; ++ct){
        float z2 = fmaf(-2.0f*mm, rv[ct], zch[ct]);
        u2[ct] = z2 - a[ct];
        uu2 = fmaf(u2[ct], u2[ct], uu2);
      }
      uu2 = red16(uu2);
      float f2 = r2 / fmaxf(uu2, MINN);
      #pragma unroll
      for (int ct = 0; ct < 8; ++ct)
        zout[row*HD + ct*16 + l15] = fmaf(f2, u2[ct], a[ct]);
    }
  }

  if constexpr (WRITE_OUT || WRITE_HB){
    #pragma unroll
    for (int ct = 0; ct < 8; ++ct)
      #pragma unroll
      for (int q = 0; q < 4; ++q){
        float v = acc[ct][q];
        long row = rb + kg*4 + q;
        if (WRITE_OUT) out[row*HD + ct*16 + l15] = v;
        if (WRITE_HB) hbout[row*HD + ct*16 + l15] = (unsigned short)f2bf(v);
      }
  }
}

// ---------------- BN finalize: part2[8][256] -> scale/shift; re-zero part2 ----------
__global__ __launch_bounds__(256) void bnfin_k(float* __restrict__ part2,
    const float* __restrict__ g, const float* __restrict__ b,
    float* __restrict__ scale, float* __restrict__ shift){
  __shared__ float sm[256];
  float tot = 0.f;
  #pragma unroll
  for (int r = 0; r < 8; ++r) tot += part2[r*256 + threadIdx.x];
  sm[threadIdx.x] = tot;
  __syncthreads();
  if (threadIdx.x < 128){
    int c = threadIdx.x;
    float s = sm[c], q = sm[c + 128];
    float mu  = s * (1.0f/NN);
    float var = q * (1.0f/NN) - mu*mu;
    float istd = rsqrtf(var + 1e-5f);
    float scv = g[c]*istd;
    scale[c] = scv;
    shift[c] = fmaf(-mu, scv, b[c]);
  }
  #pragma unroll
  for (int r = 0; r < 8; ++r) part2[r*256 + threadIdx.x] = 0.f;
}

extern "C" void kernel_launch(void* const* d_in, const int* in_sizes, int n_in,
                              void* d_out, int out_size, void* d_ws, size_t ws_size,
                              hipStream_t stream) {
  const float* x       = (const float*)d_in[0];
  const int*   ei      = (const int*)  d_in[1];
  const float* fc0_w   = (const float*)d_in[2];
  const float* fc0_b   = (const float*)d_in[3];
  const float* w1      = (const float*)d_in[4];
  const float* b1      = (const float*)d_in[5];
  const float* gamma   = (const float*)d_in[6];
  const float* beta    = (const float*)d_in[7];
  const float* w2      = (const float*)d_in[8];
  const float* b2      = (const float*)d_in[9];
  const float* fco_w   = (const float*)d_in[10];
  const float* fco_b   = (const float*)d_in[11];
  const float* p       = (const float*)d_in[12];

  float* out = (float*)d_out;
  float* ws  = (float*)d_ws;

  float* h     = ws;                     // [NN*HD] f32
  float* zA    = h   + (size_t)NN*HD;
  float* zB    = zA  + (size_t)NN*HD;
  float* part2 = zB  + (size_t)NN*HD;    // [8*256]
  float* scale = part2 + 8*256;          // [128]
  float* shift = scale + 128;            // [128]
  bf16x8* bhi  = (bf16x8*)(shift + 128); // [8*2048]
  bf16x8* blo  = bhi + 8*2048;           // [8*2048]
  unsigned short* hb = (unsigned short*)(blo + 8*2048); // [NN*HD] bf16 mirror
  int* cnt     = (int*)(hb + (size_t)NN*HD);
  int* ptr     = cnt + NN;               // [NN+1]
  int* fil     = ptr + NN + 1;           // [NN]
  unsigned short* eidx = (unsigned short*)(fil + NN);   // [NE] (u16 src ids)
  int* locpre  = (int*)(eidx + NE);      // [NSB*256]
  int* btot    = locpre + NSB*256;       // [NSB]
  float* t = out;                        // reuse d_out as the w1-activation buffer

  const int* src = ei;
  const int* dst = ei + NE;
  const float scaling = tanhf(0.5f);

  // K1: weight prep + zero cnt/part2
  zero_prep_k<<<417, 64, 0, stream>>>(fc0_w, w1, w2, fco_w, bhi, blo, cnt, part2);

  // K2: fc0 tiles (h, hb, zinit->zB) + edge histogram
  fc0hist_k<<<GB + HB_BLK, 64, 0, stream>>>(x, dst, cnt, bhi, blo, fc0_b,
                                            h, hb, zB, scaling);

  // K3-K5: scan + fill (CSR by dst)
  scan1_k<<<NSB, 256, 0, stream>>>(cnt, locpre, btot);
  scan23_k<<<NSB, 256, 0, stream>>>(btot, locpre, ptr, fil);
  fill_k<<<512, 256, 0, stream>>>(src, dst, fil, eidx, NE);

  float* zprev = zA; float* zcur = zB;

  for (int i = 0; i < 3; ++i) {
    // t = relu((h + agg(h)) @ w1^T + b1); 4-wave gather; stats -> atomic part2
    gw1_k<<<GB, 256, 0, stream>>>(
        h, bhi + (1+i)*2048, blo + (1+i)*2048, b1 + i*HD, t, part2,
        (const uint4*)hb, ptr, eidx);
    bnfin_k<<<1, 256, 0, stream>>>(part2, gamma + i*HD, beta + i*HD, scale, shift);
    // h = relu( BN(t) @ w2^T + b2 ) + fused hyperbolic z-step (hoisted z loads).
    if (i == 0)
      mgemm_k<true,true,false,false,true,true,true,true>
          <<<GB, 64, 0, stream>>>(
          t, bhi + 4*2048, blo + 4*2048, b2, scale, shift, h, hb,
          zprev, scaling, zprev, zcur, p);
    else if (i == 1)
      mgemm_k<true,true,false,false,true,true,true,false>
          <<<GB, 64, 0, stream>>>(
          t, bhi + 5*2048, blo + 5*2048, b2 + HD, scale, shift, h, hb,
          zprev, scaling, zprev, zcur, p);
    else
      mgemm_k<true,true,false,false,false,false,true,false>
          <<<GB, 64, 0, stream>>>(
          t, bhi + 6*2048, blo + 6*2048, b2 + 2*HD, scale, shift, h, nullptr,
          zprev, scaling, zprev, zcur, p);
    float* tmp = zprev; zprev = zcur; zcur = tmp;
  }

  // out = normalize( logmap0(z_cur) @ fc_out^T + fc_out_b )
  mgemm_k<false,false,true,true,false,true,false,false>
      <<<GB, 64, 0, stream>>>(
      zcur, bhi + 7*2048, blo + 7*2048, fco_b, nullptr, nullptr, out,
      nullptr, nullptr, 0.f, nullptr, nullptr, nullptr);
}